// Round 6
// baseline (475.426 us; speedup 1.0000x reference)
//
#include <hip/hip_runtime.h>
#include <hip/hip_bf16.h>
#include <cstdint>
#include <cstddef>

// Problem constants
#define BMC 32    // B*M
#define NNODE 1024
#define DIN 128
#define PPROJ 64
#define NCLUS 10
#define FOUT 128
#define KNB 10

// Inputs: fp32 (probe-confirmed). Output: fp32 (documented contract; R4/R5's
// identical 1.742 absmax == half-shifted bf16-in-fp32-buffer signature).
// Internals: fp32 everywhere except Ek (bf16, overlays dead Z region).
// X_trans fp32 (16 MB) lives in d_out; k_final overwrites d_out with output.
static const size_t OFF_Z    = 0;          // 2,097,152  Z fp32 [32,1024,64] -> later Ek bf16 [32,1024,128]
static const size_t OFF_SQ   = 2097152;    // 32,768     ||Z||^2
static const size_t OFF_HC   = 2129920;    // 327,680    softmax cluster H [32,1024,10] fp32
static const size_t OFF_IDX  = 2457600;    // 327,680    (int) knn indices [32,1024,10]
static const size_t OFF_CNT  = 2785280;    // 32,768     (int) edge in-degree  [ZEROED]
static const size_t OFF_FILL = 2818048;    // 32,768     (int) CSR fill ptrs   [ZEROED]
static const size_t OFF_EC   = 2850816;    // 40,960     cluster edge feats    [ZEROED]
static const size_t OFF_DCV  = 2891776;    // 320        cluster edge degrees  [ZEROED]
static const size_t OFF_OFFS = 2892096;    // 32,768     (int) CSR offsets
static const size_t OFF_ADJ  = 2924864;    // 327,680    (int) CSR adjacency (node ids)
static const size_t OFF_FLAG = 3252544;    // 1          (int) input-dtype flag (1 = bf16 inputs)
static const size_t OFF_END  = 3252608;
static const size_t ZERO_N   = OFF_OFFS - OFF_CNT;   // contiguous words to zero

__device__ __forceinline__ float bfu(unsigned int lo16) {   // low 16 bits = bf16
    return __uint_as_float(lo16 << 16);
}
__device__ __forceinline__ float bfhi(unsigned int w) {     // high 16 bits = bf16
    return __uint_as_float(w & 0xffff0000u);
}
// dtype-flexible scalar load (probe keeps us safe if inputs ever flip to bf16)
__device__ __forceinline__ float ldf(const void* p, size_t i, bool isbf) {
    return isbf ? bfu((unsigned int)((const unsigned short*)p)[i])
                : ((const float*)p)[i];
}

// ---------------------------------------------------------------------------
// Probe input dtype (worked in R4: selected fp32, finite results).
// ---------------------------------------------------------------------------
__global__ __launch_bounds__(256) void k_probe(const unsigned int* __restrict__ xw,
                                               int* __restrict__ flag) {
    __shared__ int red[256];
    int t = threadIdx.x;
    int cnt = 0;
    for (int i = t; i < 1024; i += 256) {
        float b = bfu(xw[i] & 0xffffu);
        float ab = fabsf(b);
        if (ab > 9.5e-7f && ab < 1.0e6f) cnt++;
    }
    red[t] = cnt;
    __syncthreads();
    for (int off = 128; off > 0; off >>= 1) {
        if (t < off) red[t] += red[t + off];
        __syncthreads();
    }
    if (t == 0) flag[0] = (red[0] >= 700) ? 1 : 0;
}

__global__ __launch_bounds__(256) void k_zero(float* __restrict__ p, int n) {
    int i = blockIdx.x * 256 + threadIdx.x;
    if (i < n) p[i] = 0.0f;
}

// ---------------------------------------------------------------------------
// Kernel 1: Z = x_flat @ Wp^T + b ; sq = ||Z||^2 ; Hc = softmax(Z @ C^T)
// block = 256, grid = 32 bm * 32 row-tiles (32 rows each).
// Phase 2 uses 8-lane shuffles (proven correct: R4 == R5 bit-identical).
// ---------------------------------------------------------------------------
__global__ __launch_bounds__(256) void k_proj(const void* __restrict__ x,
                                              const void* __restrict__ Wp,
                                              const void* __restrict__ Wpb,
                                              const void* __restrict__ Cm,
                                              const int* __restrict__ flag,
                                              float* __restrict__ Z,
                                              float* __restrict__ sqv,
                                              float* __restrict__ Hc) {
    __shared__ float xs[32][132];   // x rows fp32 (pad +4)
    __shared__ float wpT[128][65];  // Wp transposed [d][p]
    __shared__ float cs[10][64];    // C
    __shared__ float zs[32][68];    // Z tile

    const bool isbf = (flag[0] != 0);
    int tid = threadIdx.x;
    int bi  = blockIdx.x;
    int bm  = bi >> 5;
    int n0  = (bi & 31) << 5;
    int b   = bm >> 3, m = bm & 7;

    if (isbf) {
        const unsigned short* xp = (const unsigned short*)x;
        for (int e = tid; e < 512; e += 256) {
            int r = e >> 4, h = e & 15;
            uint4 u = *(const uint4*)(xp + ((((size_t)b * NNODE + n0 + r) * 8 + m) * DIN + h * 8));
            int c = h * 8;
            xs[r][c+0] = bfu(u.x & 0xffffu); xs[r][c+1] = bfhi(u.x);
            xs[r][c+2] = bfu(u.y & 0xffffu); xs[r][c+3] = bfhi(u.y);
            xs[r][c+4] = bfu(u.z & 0xffffu); xs[r][c+5] = bfhi(u.z);
            xs[r][c+6] = bfu(u.w & 0xffffu); xs[r][c+7] = bfhi(u.w);
        }
    } else {
        const float* xp = (const float*)x;
        for (int e = tid; e < 1024; e += 256) {
            int r = e >> 5, q = e & 31;
            *(float4*)&xs[r][q * 4] =
                *(const float4*)(xp + ((((size_t)b * NNODE + n0 + r) * 8 + m) * DIN + q * 4));
        }
    }
    for (int e = tid; e < 8192; e += 256) {
        int p = e >> 7, d = e & 127;
        wpT[d][p] = ldf(Wp, (size_t)p * 128 + d, isbf);
    }
    for (int e = tid; e < 640; e += 256) cs[e >> 6][e & 63] = ldf(Cm, e, isbf);
    __syncthreads();

    // each thread: 8 rows x 1 p-column
    int rg = tid >> 6, p = tid & 63;
    float acc[8] = {0.f,0.f,0.f,0.f,0.f,0.f,0.f,0.f};
    for (int d4 = 0; d4 < 32; ++d4) {
        float w0 = wpT[d4*4+0][p], w1 = wpT[d4*4+1][p];
        float w2 = wpT[d4*4+2][p], w3 = wpT[d4*4+3][p];
#pragma unroll
        for (int j = 0; j < 8; ++j) {
            float4 xv = *(const float4*)&xs[rg*8+j][d4*4];
            acc[j] += xv.x*w0 + xv.y*w1 + xv.z*w2 + xv.w*w3;
        }
    }
    float bias = ldf(Wpb, p, isbf);
#pragma unroll
    for (int j = 0; j < 8; ++j) {
        float v = acc[j] + bias;
        zs[rg*8+j][p] = v;
        Z[((size_t)bm * NNODE + n0 + rg*8 + j) * 64 + p] = v;
    }
    __syncthreads();

    // per-row sq + cluster softmax: 8 threads per row (shuffles proven correct)
    int row = tid >> 3, slot = tid & 7;
    int d0 = slot * 8;
    float sp = 0.f;
#pragma unroll
    for (int dd = 0; dd < 8; ++dd) { float z = zs[row][d0+dd]; sp += z * z; }
#pragma unroll
    for (int mm = 1; mm < 8; mm <<= 1) sp += __shfl_xor(sp, mm, 8);
    size_t g = (size_t)bm * NNODE + n0 + row;
    if (slot == 0) sqv[g] = sp;

    float sc[10];
#pragma unroll
    for (int c = 0; c < 10; ++c) {
        float pa = 0.f;
#pragma unroll
        for (int dd = 0; dd < 8; ++dd) pa += zs[row][d0+dd] * cs[c][d0+dd];
#pragma unroll
        for (int mm = 1; mm < 8; mm <<= 1) pa += __shfl_xor(pa, mm, 8);
        sc[c] = pa;
    }
    float mx = sc[0];
#pragma unroll
    for (int c = 1; c < 10; ++c) mx = fmaxf(mx, sc[c]);
    float ssum = 0.f;
#pragma unroll
    for (int c = 0; c < 10; ++c) { sc[c] = expf(sc[c] - mx); ssum += sc[c]; }
    float inv = 1.0f / ssum;
#pragma unroll
    for (int c = 0; c < 10; ++c)
        if ((c & 7) == slot) Hc[g * 10 + c] = sc[c] * inv;
}

// ---------------------------------------------------------------------------
// Kernel 2: X_trans = x_flat @ Theta^T + b  -> fp32, stored in d_out (16 MB)
// ---------------------------------------------------------------------------
__global__ __launch_bounds__(256) void k_theta(const void* __restrict__ x,
                                               const void* __restrict__ Th,
                                               const void* __restrict__ Thb,
                                               const int* __restrict__ flag,
                                               float* __restrict__ Xt) {
    __shared__ float xs[32][132];
    __shared__ float thT[64][132];  // k-chunk of Theta transposed [dk][f]

    const bool isbf = (flag[0] != 0);
    int tid = threadIdx.x;
    int bi  = blockIdx.x;
    int bm  = bi >> 5;
    int n0  = (bi & 31) << 5;
    int b   = bm >> 3, m = bm & 7;

    if (isbf) {
        const unsigned short* xp = (const unsigned short*)x;
        for (int e = tid; e < 512; e += 256) {
            int r = e >> 4, h = e & 15;
            uint4 u = *(const uint4*)(xp + ((((size_t)b * NNODE + n0 + r) * 8 + m) * DIN + h * 8));
            int c = h * 8;
            xs[r][c+0] = bfu(u.x & 0xffffu); xs[r][c+1] = bfhi(u.x);
            xs[r][c+2] = bfu(u.y & 0xffffu); xs[r][c+3] = bfhi(u.y);
            xs[r][c+4] = bfu(u.z & 0xffffu); xs[r][c+5] = bfhi(u.z);
            xs[r][c+6] = bfu(u.w & 0xffffu); xs[r][c+7] = bfhi(u.w);
        }
    } else {
        const float* xp = (const float*)x;
        for (int e = tid; e < 1024; e += 256) {
            int r = e >> 5, q = e & 31;
            *(float4*)&xs[r][q * 4] =
                *(const float4*)(xp + ((((size_t)b * NNODE + n0 + r) * 8 + m) * DIN + q * 4));
        }
    }

    int rg = tid >> 7, f = tid & 127;   // 16 rows x 1 f-column per thread
    float acc[16];
#pragma unroll
    for (int j = 0; j < 16; ++j) acc[j] = 0.f;

    for (int kc = 0; kc < 2; ++kc) {
        __syncthreads();
        for (int e = tid; e < 8192; e += 256) {
            int ff = e >> 6, dk = e & 63;
            thT[dk][ff] = ldf(Th, (size_t)ff * 128 + kc * 64 + dk, isbf);
        }
        __syncthreads();
        for (int dk4 = 0; dk4 < 16; ++dk4) {
            float w0 = thT[dk4*4+0][f], w1 = thT[dk4*4+1][f];
            float w2 = thT[dk4*4+2][f], w3 = thT[dk4*4+3][f];
            int dbase = kc * 64 + dk4 * 4;
#pragma unroll
            for (int j = 0; j < 16; ++j) {
                float4 xv = *(const float4*)&xs[rg*16+j][dbase];
                acc[j] += xv.x*w0 + xv.y*w1 + xv.z*w2 + xv.w*w3;
            }
        }
    }
    float bias = ldf(Thb, f, isbf);
#pragma unroll
    for (int j = 0; j < 16; ++j)
        Xt[((size_t)bm * NNODE + n0 + rg*16 + j) * 128 + f] = acc[j] + bias;
}

// ---------------------------------------------------------------------------
// Kernel 3: fused Gram + top-K.  block=256, grid = 32 bm * 16 row-tiles.
// 4 threads/row scan + shuffle merge (proven correct: R4 == R5 bit-identical).
// ---------------------------------------------------------------------------
__global__ __launch_bounds__(256) void k_topk(const float* __restrict__ Z,
                                              const float* __restrict__ sqv,
                                              int* __restrict__ idxo,
                                              int* __restrict__ cnt) {
    __shared__ float As[64][68];   // A tile transposed [k][row]
    __shared__ float BS[8704];     // union: B [128][68] / scores S [64][132]
    __shared__ float sqt[128];

    int tid = threadIdx.x;
    int bi  = blockIdx.x;
    int bm  = bi >> 4;
    int n0  = (bi & 15) << 6;
    const float* Zb = Z + (size_t)bm * NNODE * 64;

    for (int e = tid; e < 4096; e += 256) {
        int r = e >> 6, k = e & 63;
        As[k][r] = Zb[(n0 + r) * 64 + k];
    }

    unsigned long long keys[10];
#pragma unroll
    for (int j = 0; j < 10; ++j) keys[j] = ~0ULL;

    int rg = tid >> 5, cg = tid & 31;   // compute: 8 rows x 4 cols (stride 32)
    int r0 = rg * 8;
    int srow = tid >> 2, sslot = tid & 3;  // scan: 4 threads/row

    for (int t8 = 0; t8 < 8; ++t8) {
        int j0 = t8 << 7;
        for (int e = tid; e < 8192; e += 256) {
            int c = e >> 6, k = e & 63;
            BS[c * 68 + k] = Zb[(j0 + c) * 64 + k];
        }
        if (tid < 128) sqt[tid] = sqv[(size_t)bm * NNODE + j0 + tid];
        __syncthreads();

        float acc[8][4];
#pragma unroll
        for (int j = 0; j < 8; ++j)
#pragma unroll
            for (int q = 0; q < 4; ++q) acc[j][q] = 0.f;

        for (int k4 = 0; k4 < 16; ++k4) {
            float bcol[4][4];
#pragma unroll
            for (int q = 0; q < 4; ++q) {
                float4 t = *(const float4*)&BS[(cg + 32*q) * 68 + k4 * 4];
                bcol[q][0]=t.x; bcol[q][1]=t.y; bcol[q][2]=t.z; bcol[q][3]=t.w;
            }
#pragma unroll
            for (int kk = 0; kk < 4; ++kk) {
                int k = (k4 << 2) + kk;
                float4 a0 = *(const float4*)&As[k][r0];
                float4 a1 = *(const float4*)&As[k][r0 + 4];
#pragma unroll
                for (int q = 0; q < 4; ++q) {
                    float bb = bcol[q][kk];
                    acc[0][q] += a0.x*bb; acc[1][q] += a0.y*bb;
                    acc[2][q] += a0.z*bb; acc[3][q] += a0.w*bb;
                    acc[4][q] += a1.x*bb; acc[5][q] += a1.y*bb;
                    acc[6][q] += a1.z*bb; acc[7][q] += a1.w*bb;
                }
            }
        }
        __syncthreads();   // all B reads done before overwriting with scores

#pragma unroll
        for (int q = 0; q < 4; ++q) {
            int c = cg + 32 * q;
            float sqc = sqt[c];
#pragma unroll
            for (int j = 0; j < 8; ++j)
                BS[(r0 + j) * 132 + c] = fmaf(-2.f, acc[j][q], sqc);
        }
        __syncthreads();

        // scan 32 cols per thread (stride-4 interleave keeps banks spread)
        for (int i = 0; i < 32; ++i) {
            int c = sslot + (i << 2);
            float v = BS[srow * 132 + c];
            unsigned int bits = __float_as_uint(v);
            unsigned int s = (bits & 0x80000000u) ? ~bits : (bits | 0x80000000u);
            unsigned long long key =
                ((unsigned long long)s << 32) | (unsigned int)(j0 + c);
            if (key < keys[9]) {
                keys[9] = key;
#pragma unroll
                for (int j = 9; j > 0; --j) {
                    if (keys[j] < keys[j-1]) {
                        unsigned long long t = keys[j];
                        keys[j] = keys[j-1]; keys[j-1] = t;
                    }
                }
            }
        }
        __syncthreads();   // scans done before next tile's B load
    }

    // merge 4 slots/row: 10 rounds of min-extraction via shuffles
    for (int it = 0; it < 10; ++it) {
        unsigned long long mine = keys[0];
        unsigned long long best = mine;
#pragma unroll
        for (int mm = 1; mm < 4; mm <<= 1) {
            unsigned long long o = __shfl_xor(best, mm, 4);
            if (o < best) best = o;
        }
        if (best == mine) {   // this slot's candidate won: pop
#pragma unroll
            for (int j = 0; j < 9; ++j) keys[j] = keys[j+1];
            keys[9] = ~0ULL;
        }
        if (sslot == 0) {
            int col = (int)(best & 0xFFFFFFFFu);
            idxo[((size_t)bm * NNODE + n0 + srow) * KNB + it] = col;
            atomicAdd(&cnt[bm * NNODE + col], 1);
        }
    }
}

// ---------------------------------------------------------------------------
// CSR build: per-bm exclusive scan of in-degrees, then fill
// ---------------------------------------------------------------------------
__global__ __launch_bounds__(256) void k_scan(const int* __restrict__ cnt,
                                              int* __restrict__ offs) {
    __shared__ int part[256];
    int bm = blockIdx.x, t = threadIdx.x;
    int base = bm * 1024 + t * 4;
    int c0 = cnt[base], c1 = cnt[base+1], c2 = cnt[base+2], c3 = cnt[base+3];
    int ps = c0 + c1 + c2 + c3;
    part[t] = ps;
    __syncthreads();
    for (int off = 1; off < 256; off <<= 1) {
        int add = (t >= off) ? part[t - off] : 0;
        __syncthreads();
        part[t] += add;
        __syncthreads();
    }
    int e0 = part[t] - ps;           // exclusive base
    int gb = bm * (NNODE * KNB);     // 10240 per bm
    offs[base]   = gb + e0;
    offs[base+1] = gb + e0 + c0;
    offs[base+2] = gb + e0 + c0 + c1;
    offs[base+3] = gb + e0 + c0 + c1 + c2;
}

__global__ __launch_bounds__(256) void k_fill(const int* __restrict__ idxb,
                                              const int* __restrict__ offs,
                                              int* __restrict__ fill,
                                              int* __restrict__ adj) {
    int i = blockIdx.x * 256 + threadIdx.x;  // 327,680 pairs
    int g = i / 10;
    int bm = g >> 10;
    int e  = idxb[i];
    int eg = (bm << 10) + e;
    int pos = atomicAdd(&fill[eg], 1);
    adj[offs[eg] + pos] = g;
}

// ---------------------------------------------------------------------------
// kNN edge gather: Ek[e] = (1/De) * sum_{n in members(e)} Xt[n]   (bf16 out)
// ---------------------------------------------------------------------------
__global__ __launch_bounds__(256) void k_edge(const float* __restrict__ Xt,
                                              const int* __restrict__ offs,
                                              const int* __restrict__ cnt,
                                              const int* __restrict__ adj,
                                              __hip_bfloat16* __restrict__ Ek) {
    int tid = threadIdx.x;
    int e = blockIdx.x * 2 + (tid >> 7);
    int f = tid & 127;
    int start = offs[e];
    int num = cnt[e];
    float acc = 0.f;
    for (int i = 0; i < num; ++i) {
        int g = adj[start + i];
        acc += Xt[(size_t)g * 128 + f];
    }
    float scale = (num > 0) ? 1.0f / (float)num : 0.0f;
    Ek[(size_t)e * 128 + f] = __float2bfloat16(acc * scale);
}

// ---------------------------------------------------------------------------
// Cluster edges: Ec[c] = sum_n Hc[n,c]*Xt[n], Dcv[c] = sum_n Hc[n,c]
// ---------------------------------------------------------------------------
__global__ __launch_bounds__(256) void k_clus(const float* __restrict__ Xt,
                                              const float* __restrict__ Hc,
                                              float* __restrict__ Ec,
                                              float* __restrict__ Dcv) {
    int tid = threadIdx.x;
    int bm = blockIdx.x >> 3;
    int ch = blockIdx.x & 7;
    int f = tid & 127;
    int h = tid >> 7;
    int c0 = h * 5;
    float acc[5]  = {0.f,0.f,0.f,0.f,0.f};
    float dacc[5] = {0.f,0.f,0.f,0.f,0.f};
    int n0 = ch * 128;
    for (int n = n0; n < n0 + 128; ++n) {
        size_t g = (size_t)bm * NNODE + n;
        float xv = Xt[g * 128 + f];
#pragma unroll
        for (int j = 0; j < 5; ++j) {
            float hv = Hc[g * 10 + c0 + j];
            acc[j]  += hv * xv;
            dacc[j] += hv;
        }
    }
#pragma unroll
    for (int j = 0; j < 5; ++j)
        atomicAdd(&Ec[((size_t)bm * 10 + c0 + j) * 128 + f], acc[j]);
    if (f == 0) {
#pragma unroll
        for (int j = 0; j < 5; ++j) atomicAdd(&Dcv[bm * 10 + c0 + j], dacc[j]);
    }
}

__global__ __launch_bounds__(256) void k_escale(float* __restrict__ Ec,
                                                const float* __restrict__ Dcv) {
    int i = blockIdx.x * 256 + threadIdx.x;  // 40,960
    float d = Dcv[i >> 7];
    Ec[i] = (d > 0.f) ? Ec[i] / d : 0.f;
}

// ---------------------------------------------------------------------------
// Final: node gather over kNN + cluster edges, *(1/11), ELU, layout transpose
// ---------------------------------------------------------------------------
__global__ __launch_bounds__(256) void k_final(const unsigned short* __restrict__ Ek,
                                               const float* __restrict__ Ec,
                                               const float* __restrict__ Hc,
                                               const int* __restrict__ idxb,
                                               float* __restrict__ out) {
    int tid = threadIdx.x;
    int g = blockIdx.x * 2 + (tid >> 7);
    int f = tid & 127;
    int bm = g >> 10, n = g & 1023;
    const int* ip = idxb + (size_t)g * 10;
    float acc = 0.f;
#pragma unroll
    for (int k = 0; k < 10; ++k) {
        int e = ip[k];
        acc += bfu((unsigned int)Ek[((size_t)(bm << 10) + e) * 128 + f]);
    }
    const float* hp  = Hc + (size_t)g * 10;
    const float* ecp = Ec + (size_t)bm * 10 * 128 + f;
#pragma unroll
    for (int c = 0; c < 10; ++c) acc += hp[c] * ecp[c * 128];
    float r = acc * (1.0f / 11.0f);   // D_v == 11 exactly -> fold both Dv^-1/2
    r = (r > 0.f) ? r : expm1f(r);
    int b = bm >> 3, m = bm & 7;
    out[(((size_t)b * NNODE + n) * 8 + m) * 128 + f] = r;
}

// ---------------------------------------------------------------------------
extern "C" void kernel_launch(void* const* d_in, const int* in_sizes, int n_in,
                              void* d_out, int out_size, void* d_ws, size_t ws_size,
                              hipStream_t stream) {
    const void* x   = d_in[0];
    const void* Wp  = d_in[1];
    const void* Wpb = d_in[2];
    const void* Cm  = d_in[3];
    const void* Th  = d_in[4];
    const void* Thb = d_in[5];
    float* ws = (float*)d_ws;

    if (ws_size < OFF_END * sizeof(float)) return;  // fail validation, not crash

    float* Z    = ws + OFF_Z;
    float* sqv  = ws + OFF_SQ;
    float* Hc   = ws + OFF_HC;
    int*   idxb = (int*)(ws + OFF_IDX);
    int*   cnt  = (int*)(ws + OFF_CNT);
    int*   fill = (int*)(ws + OFF_FILL);
    float* Ec   = ws + OFF_EC;
    float* Dcv  = ws + OFF_DCV;
    int*   offs = (int*)(ws + OFF_OFFS);
    int*   adj  = (int*)(ws + OFF_ADJ);
    int*   flag = (int*)(ws + OFF_FLAG);
    __hip_bfloat16* Ek = (__hip_bfloat16*)(ws + OFF_Z);   // overlays dead Z
    float* Xt  = (float*)d_out;                           // d_out as fp32 scratch (16 MB)
    float* out = (float*)d_out;

    k_probe <<<1, 256, 0, stream>>>((const unsigned int*)x, flag);
    k_zero  <<<(int)((ZERO_N + 255) / 256), 256, 0, stream>>>(ws + OFF_CNT, (int)ZERO_N);
    k_proj  <<<1024, 256, 0, stream>>>(x, Wp, Wpb, Cm, flag, Z, sqv, Hc);
    k_topk  <<<512,  256, 0, stream>>>(Z, sqv, idxb, cnt);
    k_scan  <<<32,   256, 0, stream>>>(cnt, offs);
    k_fill  <<<1280, 256, 0, stream>>>(idxb, offs, fill, adj);
    k_theta <<<1024, 256, 0, stream>>>(x, Th, Thb, flag, Xt);
    k_edge  <<<16384,256, 0, stream>>>(Xt, offs, cnt, adj, Ek);   // Ek overlays dead Z
    k_clus  <<<256,  256, 0, stream>>>(Xt, Hc, Ec, Dcv);
    k_escale<<<160,  256, 0, stream>>>(Ec, Dcv);
    k_final <<<16384,256, 0, stream>>>((const unsigned short*)Ek, Ec, Hc, idxb, out);
}